// Round 5
// baseline (176.095 us; speedup 1.0000x reference)
//
#include <hip/hip_runtime.h>

#define NB 64        // bins
#define HW 65536     // pixels per channel (256*256)
#define NCH 24       // B*C = 8*3
#define SPLIT 32     // segments per channel-image
#define NPAIR 38     // 76 slots as 38 float2 pairs; slot = bin + 6, bins -6..69

// w_j(x) = exp(-K*(f-j)^2), f = 63x, K = 2048/3969.
// Even-aligned 12-tap window: e0 = (rint(f)-5) & ~1 (even), c0 = e0+6,
// d' = f - c0 in [-1.5, 0.5]; taps r = -6..5 -> bins e0..e0+11, a strict
// superset of the +-5 window (same truncation quality as r0: dropped mass
// at distance >= 5.5 bins, < 1.5e-7 relative). w(r) = w0 * mp^r * exp(-K r^2).
//
// LDS: H[pair][256] float2 -> a pixel's 12 taps = 6 ALIGNED float2 cells at
// stride 2048 B => 6 ds_read_b64 + 6 ds_write_b64 (imm offsets), bank pattern
// (2*tid+{0,1})%32 uniform (b64 data-path floor, no conflict surplus).
// Private per-thread columns => no atomics (r1: ds atomic ~200 cy), no races;
// same-wave DS ops complete in order => per-pixel RMW is RAW-safe.
// NOTE (r3 lesson): NO device fences / completion atomics here — the fused
// tail cost ~90us in fences. Plain 2-launch structure instead.
__global__ __launch_bounds__(256) void chml_hist(const float* __restrict__ pred,
                                                 const float* __restrict__ targ,
                                                 float* __restrict__ part) {
  const int seg = blockIdx.x;   // 0..SPLIT-1
  const int ct  = blockIdx.y;   // 0..2*NCH-1
  const float* src = (ct < NCH) ? (pred + (size_t)ct * HW)
                                : (targ + (size_t)(ct - NCH) * HW);
  const int tid = threadIdx.x;

  // issue global loads first (in flight during LDS init)
  const float4* s4 = (const float4*)(src + (size_t)seg * (HW / SPLIT));
  float4 P0 = s4[tid];
  float4 P1 = s4[256 + tid];

  __shared__ float2 H[NPAIR][256];   // 77824 B -> 2 blocks/CU
  {
    float4* hz = (float4*)&H[0][0];
#pragma unroll
    for (int i = tid; i < NPAIR * 256 * 2 / 4; i += 256)
      hz[i] = make_float4(0.f, 0.f, 0.f, 0.f);
  }
  __syncthreads();

  const float K  = 0.51599899f;      // 2048/3969
  const float C1 = 5.96905619e-01f;  // exp(-K*1)
  const float C2 = 1.26927917e-01f;  // exp(-K*4)
  const float C3 = 9.61165782e-03f;  // exp(-K*9)
  const float C4 = 2.59240329e-04f;  // exp(-K*16)
  const float C5 = 2.49029640e-06f;  // exp(-K*25)
  const float C6 = 8.56260000e-09f;  // exp(-K*36)

  float2* const hb = &H[0][tid];     // pair stride = 256 float2 = 2048 B

#pragma unroll
  for (int k2 = 0; k2 < 2; ++k2) {
    float4 p = (k2 == 0) ? P0 : P1;
    float pe[4] = {p.x, p.y, p.z, p.w};
#pragma unroll
    for (int e = 0; e < 4; ++e) {
      float f  = pe[e] * 63.0f;
      float n  = rintf(f);
      int   ni = (int)n;                        // 0..63
      int   e0 = (ni - 5) & ~1;                 // even, in [-6, 58]
      float dp = f - (float)(e0 + 6);           // d' in [-1.5, 0.5]
      float2* tp = hb + (((e0 >> 1) + 3) << 8); // pair p0 = (e0+6)/2 in [0,32]
      // ---- issue the 6 b64 tap reads first (latency hidden by the ladder)
      float2 t[6];
#pragma unroll
      for (int j = 0; j < 6; ++j) t[j] = tp[j * 256];
      // ---- weight ladder (independent of the reads)
      float w0 = __expf(dp * dp * -K);
      float mp = __expf(dp * (2.0f * K));
      float mn = __expf(dp * (-2.0f * K));
      float mp2 = mp * mp, mp3 = mp2 * mp, mp4 = mp2 * mp2, mp5 = mp4 * mp;
      float mn2 = mn * mn, mn3 = mn2 * mn, mn4 = mn2 * mn2, mn5 = mn4 * mn,
            mn6 = mn3 * mn3;
      float A1 = w0 * C1, A2 = w0 * C2, A3 = w0 * C3, A4 = w0 * C4,
            A5 = w0 * C5, A6 = w0 * C6;
      float2 w[6];
      w[0] = make_float2(A6 * mn6, A5 * mn5);  // r = -6, -5
      w[1] = make_float2(A4 * mn4, A3 * mn3);
      w[2] = make_float2(A2 * mn2, A1 * mn);
      w[3] = make_float2(w0,       A1 * mp);   // r = 0, +1
      w[4] = make_float2(A2 * mp2, A3 * mp3);
      w[5] = make_float2(A4 * mp4, A5 * mp5);  // r = +4, +5
      // ---- RMW writeback (6 ds_write_b64)
#pragma unroll
      for (int j = 0; j < 6; ++j)
        tp[j * 256] = make_float2(t[j].x + w[j].x, t[j].y + w[j].y);
    }
  }
  __syncthreads();

  // Fold 256 columns -> 1 per pair. Lane l (<38) owns pair l; wave wv sums
  // rows [64wv, 64wv+64) with staggered row order (i+l)&63 -> uniform b64
  // banks, conflict-free.
  const int wv = tid >> 6, l = tid & 63;
  float2 facc = make_float2(0.f, 0.f);
  if (l < NPAIR) {
    const float2* col = &H[l][wv << 6];
#pragma unroll 8
    for (int i = 0; i < 64; ++i) {
      float2 v = col[(i + l) & 63];
      facc.x += v.x; facc.y += v.y;
    }
  }
  __syncthreads();
  if (l < NPAIR) H[l][wv] = facc;   // scratch: rows 0..3 (already consumed)
  __syncthreads();
  if (tid < NPAIR) {
    float2 a = H[tid][0], b2 = H[tid][1], c2 = H[tid][2], d2 = H[tid][3];
    float sx = a.x + b2.x + c2.x + d2.x;
    float sy = a.y + b2.y + c2.y + d2.y;
    int bin0 = 2 * tid - 6;          // slot 2*tid -> bin = slot - 6
    float* dst = part + ((size_t)ct * SPLIT + seg) * NB;
    if (bin0 >= 0 && bin0 < NB) dst[bin0] = sx;
    int bin1 = bin0 + 1;
    if (bin1 >= 0 && bin1 < NB) dst[bin1] = sy;
  }
}

// Merged tail: 1 block x 256 threads (4 waves). Wave wv handles channels
// {wv, wv+4, ..., wv+20}; lane = bin. Per channel: sum segment partials
// (pred & targ), prefix-scan -> CDFs, normalize, sum |diff|; then combine
// the 4 wave sums via LDS and write the mean. (Same arithmetic that passed
// verification as r3's last-block path.)
__global__ __launch_bounds__(256) void chml_cdf(const float* __restrict__ part,
                                                float* __restrict__ out) {
  const int tid = threadIdx.x;
  const int wv = tid >> 6, l = tid & 63;
  __shared__ float wsum[4];

  float lsum = 0.f;
#pragma unroll
  for (int ci = 0; ci < 6; ++ci) {
    int c = wv + ci * 4;             // 0..23
    float vp = 0.f, vt = 0.f;
    const float* pp = part + (size_t)c * SPLIT * NB + l;
    const float* pt = part + (size_t)(c + NCH) * SPLIT * NB + l;
#pragma unroll
    for (int s = 0; s < SPLIT; ++s) { vp += pp[s * NB]; vt += pt[s * NB]; }
    // inclusive prefix scan across 64 lanes
#pragma unroll
    for (int off = 1; off < 64; off <<= 1) {
      float up = __shfl_up(vp, off, 64);
      float ut = __shfl_up(vt, off, 64);
      if (l >= off) { vp += up; vt += ut; }
    }
    float totp = __shfl(vp, 63, 64);
    float tott = __shfl(vt, 63, 64);
    lsum += fabsf(vp / (totp + 1e-7f) - vt / (tott + 1e-7f));
  }
#pragma unroll
  for (int off = 32; off >= 1; off >>= 1) lsum += __shfl_xor(lsum, off, 64);
  if (l == 0) wsum[wv] = lsum;
  __syncthreads();
  if (tid == 0)
    out[0] = (wsum[0] + wsum[1] + wsum[2] + wsum[3]) * (1.0f / (float)(NCH * NB));
}

extern "C" void kernel_launch(void* const* d_in, const int* in_sizes, int n_in,
                              void* d_out, int out_size, void* d_ws, size_t ws_size,
                              hipStream_t stream) {
  const float* pred = (const float*)d_in[0];
  const float* targ = (const float*)d_in[1];
  float* part = (float*)d_ws;        // 48*32*64 floats = 384 KB

  dim3 grid(SPLIT, 2 * NCH);
  chml_hist<<<grid, 256, 0, stream>>>(pred, targ, part);
  chml_cdf<<<1, 256, 0, stream>>>(part, (float*)d_out);
}

// Round 6
// 74.322 us; speedup vs baseline: 2.3693x; 2.3693x over previous
//
#include <hip/hip_runtime.h>

#define NB 64        // bins
#define HW 65536     // pixels per channel (256*256)
#define NCH 24       // B*C = 8*3
#define SPLIT 8      // segments per channel-image (r6: 32 -> 8, amortize init/fold)
#define NPAIR 38     // 76 slots as 38 float2 pairs; slot = bin + 6, bins -6..69

// w_j(x) = exp(-K*(f-j)^2), f = 63x, K = 2048/3969.
// Even-aligned 12-tap window: e0 = (rint(f)-5) & ~1 (even), c0 = e0+6,
// d' = f - c0 in [-1.5, 0.5]; taps r = -6..5 -> bins e0..e0+11, a strict
// superset of the +-5 window (dropped mass < 1.5e-7 relative).
// w(r) = w0 * mp^r * exp(-K r^2), 3 transcendentals, 12 taps.
//
// LDS: H[pair][256] float2 -> a pixel's 12 taps = 6 ALIGNED float2 cells at
// stride 2048 B => 6 ds_read_b64 + 6 ds_write_b64 (imm offsets), bank pattern
// (2*tid+{0,1})%32 uniform. Private per-thread columns => no atomics, no races;
// same-wave DS ops complete in order => per-pixel RMW is RAW-safe.
//
// r6 census fix: at SPLIT=32 the per-block LDS zero-init (76 b128) + fold
// (~70 DS) was 60% of DS issue, paid over 6 serial block-rounds/CU. SPLIT=8:
// 384 blocks ALL resident (2/CU, LDS 2x77.8KB fits 160KB), 32 px/thread ->
// overhead share 28%, no serial rounds.
__global__ __launch_bounds__(256) void chml_hist(const float* __restrict__ pred,
                                                 const float* __restrict__ targ,
                                                 float* __restrict__ part) {
  const int seg = blockIdx.x;   // 0..SPLIT-1
  const int ct  = blockIdx.y;   // 0..2*NCH-1
  const float* src = (ct < NCH) ? (pred + (size_t)ct * HW)
                                : (targ + (size_t)(ct - NCH) * HW);
  const int tid = threadIdx.x;

  // issue all 8 global float4 loads first (in flight during LDS init)
  const float4* s4 = (const float4*)(src + (size_t)seg * (HW / SPLIT));
  float4 P[8];
#pragma unroll
  for (int i = 0; i < 8; ++i) P[i] = s4[i * 256 + tid];

  __shared__ float2 H[NPAIR][256];   // 77824 B -> 2 blocks/CU
  {
    float4* hz = (float4*)&H[0][0];
#pragma unroll
    for (int i = tid; i < NPAIR * 256 * 2 / 4; i += 256)
      hz[i] = make_float4(0.f, 0.f, 0.f, 0.f);
  }
  __syncthreads();

  const float K  = 0.51599899f;      // 2048/3969
  const float C1 = 5.96905619e-01f;  // exp(-K*1)
  const float C2 = 1.26927917e-01f;  // exp(-K*4)
  const float C3 = 9.61165782e-03f;  // exp(-K*9)
  const float C4 = 2.59240329e-04f;  // exp(-K*16)
  const float C5 = 2.49029640e-06f;  // exp(-K*25)
  const float C6 = 8.56260000e-09f;  // exp(-K*36)

  float2* const hb = &H[0][tid];     // pair stride = 256 float2 = 2048 B

#pragma unroll
  for (int k2 = 0; k2 < 8; ++k2) {
    float4 p = P[k2];
    float pe[4] = {p.x, p.y, p.z, p.w};
#pragma unroll
    for (int e = 0; e < 4; ++e) {
      float f  = pe[e] * 63.0f;
      float n  = rintf(f);
      int   ni = (int)n;                        // 0..63
      int   e0 = (ni - 5) & ~1;                 // even, in [-6, 58]
      float dp = f - (float)(e0 + 6);           // d' in [-1.5, 0.5]
      float2* tp = hb + (((e0 >> 1) + 3) << 8); // pair p0 = (e0+6)/2 in [0,32]
      // ---- issue the 6 b64 tap reads first (latency hidden by the ladder)
      float2 t[6];
#pragma unroll
      for (int j = 0; j < 6; ++j) t[j] = tp[j * 256];
      // ---- weight ladder (independent of the reads)
      float w0 = __expf(dp * dp * -K);
      float mp = __expf(dp * (2.0f * K));
      float mn = __expf(dp * (-2.0f * K));
      float mp2 = mp * mp, mp3 = mp2 * mp, mp4 = mp2 * mp2, mp5 = mp4 * mp;
      float mn2 = mn * mn, mn3 = mn2 * mn, mn4 = mn2 * mn2, mn5 = mn4 * mn,
            mn6 = mn3 * mn3;
      float A1 = w0 * C1, A2 = w0 * C2, A3 = w0 * C3, A4 = w0 * C4,
            A5 = w0 * C5, A6 = w0 * C6;
      float2 w[6];
      w[0] = make_float2(A6 * mn6, A5 * mn5);  // r = -6, -5
      w[1] = make_float2(A4 * mn4, A3 * mn3);
      w[2] = make_float2(A2 * mn2, A1 * mn);
      w[3] = make_float2(w0,       A1 * mp);   // r = 0, +1
      w[4] = make_float2(A2 * mp2, A3 * mp3);
      w[5] = make_float2(A4 * mp4, A5 * mp5);  // r = +4, +5
      // ---- RMW writeback (6 ds_write_b64)
#pragma unroll
      for (int j = 0; j < 6; ++j)
        tp[j * 256] = make_float2(t[j].x + w[j].x, t[j].y + w[j].y);
    }
  }
  __syncthreads();

  // Fold 256 columns -> 1 per pair. Lane l (<38) owns pair l; wave wv sums
  // rows [64wv, 64wv+64) with staggered row order (i+l)&63 -> uniform b64
  // banks, conflict-free.
  const int wv = tid >> 6, l = tid & 63;
  float2 facc = make_float2(0.f, 0.f);
  if (l < NPAIR) {
    const float2* col = &H[l][wv << 6];
#pragma unroll 8
    for (int i = 0; i < 64; ++i) {
      float2 v = col[(i + l) & 63];
      facc.x += v.x; facc.y += v.y;
    }
  }
  __syncthreads();
  if (l < NPAIR) H[l][wv] = facc;   // scratch: rows 0..3 (already consumed)
  __syncthreads();
  if (tid < NPAIR) {
    float2 a = H[tid][0], b2 = H[tid][1], c2 = H[tid][2], d2 = H[tid][3];
    float sx = a.x + b2.x + c2.x + d2.x;
    float sy = a.y + b2.y + c2.y + d2.y;
    int bin0 = 2 * tid - 6;          // slot 2*tid -> bin = slot - 6
    float* dst = part + ((size_t)ct * SPLIT + seg) * NB;
    if (bin0 >= 0 && bin0 < NB) dst[bin0] = sx;
    int bin1 = bin0 + 1;
    if (bin1 >= 0 && bin1 < NB) dst[bin1] = sy;
  }
}

// Per-channel: sum segment partials, normalize, cumsum, sum |cdf diff|.
// 24 blocks x 64 threads (parallel across CUs — r5 lesson: never concentrate
// a latency-bound reduction into one block). Writes chanloss[c].
__global__ __launch_bounds__(64) void chml_chan(const float* __restrict__ part,
                                                float* __restrict__ chanloss) {
  const int c    = blockIdx.x;
  const int lane = threadIdx.x;
  float vp = 0.0f, vt = 0.0f;
#pragma unroll
  for (int s = 0; s < SPLIT; ++s) {
    vp += part[((size_t)c * SPLIT + s) * NB + lane];
    vt += part[((size_t)(c + NCH) * SPLIT + s) * NB + lane];
  }
  // inclusive prefix scan across 64 lanes
#pragma unroll
  for (int off = 1; off < 64; off <<= 1) {
    float up = __shfl_up(vp, off, 64);
    float ut = __shfl_up(vt, off, 64);
    if (lane >= off) { vp += up; vt += ut; }
  }
  float totp = __shfl(vp, 63, 64);
  float tott = __shfl(vt, 63, 64);
  float l = fabsf(vp / (totp + 1e-7f) - vt / (tott + 1e-7f));
#pragma unroll
  for (int off = 32; off >= 1; off >>= 1) l += __shfl_xor(l, off, 64);
  if (lane == 0) chanloss[c] = l;
}

// Final: mean over 24*64 terms.
__global__ __launch_bounds__(64) void chml_final(const float* __restrict__ chanloss,
                                                 float* __restrict__ out) {
  const int lane = threadIdx.x;
  float l = (lane < NCH) ? chanloss[lane] : 0.0f;
#pragma unroll
  for (int off = 32; off >= 1; off >>= 1) l += __shfl_xor(l, off, 64);
  if (lane == 0) out[0] = l * (1.0f / (float)(NCH * NB));
}

extern "C" void kernel_launch(void* const* d_in, const int* in_sizes, int n_in,
                              void* d_out, int out_size, void* d_ws, size_t ws_size,
                              hipStream_t stream) {
  const float* pred = (const float*)d_in[0];
  const float* targ = (const float*)d_in[1];
  float* part     = (float*)d_ws;                        // 48*8*64 floats = 96 KB
  float* chanloss = part + (size_t)2 * NCH * SPLIT * NB; // +24 floats

  dim3 grid(SPLIT, 2 * NCH);
  chml_hist<<<grid, 256, 0, stream>>>(pred, targ, part);
  chml_chan<<<NCH, 64, 0, stream>>>(part, chanloss);
  chml_final<<<1, 64, 0, stream>>>(chanloss, (float*)d_out);
}